// Round 1
// baseline (1062.085 us; speedup 1.0000x reference)
//
#include <hip/hip_runtime.h>
#include <math.h>

constexpr int Bn  = 32;
constexpr int Tn  = 1024;
constexpr int INn = 32;
constexpr int En  = 256;
constexpr int HDn = 64;
constexpr int Pn  = 32;
constexpr int E3n = 768;

// ---------- K0a: W_comb[768,32] = in_proj_w[768,256] @ ip_w[256,32] ----------
__global__ __launch_bounds__(256) void k_comb_w(const float* __restrict__ ipw,
                                                const float* __restrict__ inw,
                                                float* __restrict__ Wc) {
    int idx = blockIdx.x * 256 + threadIdx.x;      // 24576 total
    int o = idx >> 5, i = idx & 31;
    const float* wr = inw + (size_t)o * En;
    float a0 = 0.f, a1 = 0.f;
    for (int e = 0; e < En; e += 2) {
        a0 += wr[e]     * ipw[(size_t)e * INn + i];
        a1 += wr[e + 1] * ipw[(size_t)(e + 1) * INn + i];
    }
    Wc[(size_t)o * INn + i] = a0 + a1;
}

// ---------- K0b: b_comb = in_proj_w @ ip_b + in_proj_b ----------
__global__ __launch_bounds__(256) void k_comb_b(const float* __restrict__ ipb,
                                                const float* __restrict__ inw,
                                                const float* __restrict__ inb,
                                                float* __restrict__ bc) {
    int o = blockIdx.x * 256 + threadIdx.x;        // 768 total
    const float* wr = inw + (size_t)o * En;
    float a = inb[o];
    for (int e = 0; e < En; ++e) a += wr[e] * ipb[e];
    bc[o] = a;
}

// ---------- K1: qkv[32768,768] = x[32768,32] @ Wc^T + bc ----------
__global__ __launch_bounds__(256) void k_qkv(const float* __restrict__ x,
                                             const float* __restrict__ Wc,
                                             const float* __restrict__ bc,
                                             float* __restrict__ qkv) {
    __shared__ float xs[128][INn];
    int col = blockIdx.x * 256 + threadIdx.x;      // 0..767
    size_t row0 = (size_t)blockIdx.y * 128;
    float w[INn];
#pragma unroll
    for (int j = 0; j < INn; j += 4) {
        float4 t = *(const float4*)(Wc + (size_t)col * INn + j);
        w[j] = t.x; w[j + 1] = t.y; w[j + 2] = t.z; w[j + 3] = t.w;
    }
    float bias = bc[col];
    const float4* xv = (const float4*)(x + row0 * INn);
    float4* xsv = (float4*)&xs[0][0];
#pragma unroll
    for (int i = 0; i < 4; ++i) xsv[threadIdx.x + i * 256] = xv[threadIdx.x + i * 256];
    __syncthreads();
    float* outp = qkv + row0 * E3n + col;
#pragma unroll 2
    for (int m = 0; m < 128; ++m) {
        float a0 = bias, a1 = 0.f;
#pragma unroll
        for (int j = 0; j < INn; j += 4) {
            float4 t = *(const float4*)&xs[m][j];
            a0 += t.x * w[j];     a1 += t.y * w[j + 1];
            a0 += t.z * w[j + 2]; a1 += t.w * w[j + 3];
        }
        outp[(size_t)m * E3n] = a0 + a1;
    }
}

// ---------- K2: flash-style attention (no max-sub needed: |s| << 1) ----------
// grid 1024 = b(32) * h(4) * qtile(8).  256 thr: quad (lane&3) = d-quarter,
// tid>>2 = row-pair. ctx written back into the q-slot of qkv (race-free).
__global__ __launch_bounds__(256) void k_attn(float* __restrict__ qkv) {
    __shared__ float Ks[64][64];
    __shared__ float Vs[64][64];
    int blk = blockIdx.x;
    int qt = blk & 7;
    int h  = (blk >> 3) & 3;
    int b  = blk >> 5;
    int tid = threadIdx.x;
    int qd  = tid & 3;
    int rp  = tid >> 2;
    int r0  = qt * 128 + rp * 2;
    size_t base = (size_t)b * Tn * E3n;
    float* qrow0 = qkv + base + (size_t)r0 * E3n + h * HDn + qd * 16;
    float* qrow1 = qrow0 + E3n;

    float q0[16], q1[16], o0[16], o1[16];
#pragma unroll
    for (int j = 0; j < 16; j += 4) {
        float4 a = *(const float4*)(qrow0 + j);
        q0[j] = a.x; q0[j + 1] = a.y; q0[j + 2] = a.z; q0[j + 3] = a.w;
        float4 c = *(const float4*)(qrow1 + j);
        q1[j] = c.x; q1[j + 1] = c.y; q1[j + 2] = c.z; q1[j + 3] = c.w;
    }
#pragma unroll
    for (int j = 0; j < 16; ++j) { o0[j] = 0.f; o1[j] = 0.f; }
    float l0 = 0.f, l1 = 0.f;

    const float* kb = qkv + base + En + h * HDn;   // K slot
    for (int kt = 0; kt < 16; ++kt) {
        __syncthreads();
#pragma unroll
        for (int i = 0; i < 4; ++i) {
            int idx = tid + i * 256;               // 0..1023
            int row = idx >> 4;
            int dp  = (idx & 15) << 2;
            const float* s = kb + (size_t)(kt * 64 + row) * E3n + dp;
            *(float4*)&Ks[row][dp] = *(const float4*)s;
            *(float4*)&Vs[row][dp] = *(const float4*)(s + En);
        }
        __syncthreads();
#pragma unroll 2
        for (int kk = 0; kk < 64; ++kk) {
            const float* kr = &Ks[kk][qd * 16];
            float p0a = 0.f, p0b = 0.f, p1a = 0.f, p1b = 0.f;
#pragma unroll
            for (int j = 0; j < 16; j += 8) {
                float4 ka = *(const float4*)(kr + j);
                float4 kc = *(const float4*)(kr + j + 4);
                p0a += q0[j] * ka.x + q0[j + 1] * ka.y + q0[j + 2] * ka.z + q0[j + 3] * ka.w;
                p1a += q1[j] * ka.x + q1[j + 1] * ka.y + q1[j + 2] * ka.z + q1[j + 3] * ka.w;
                p0b += q0[j + 4] * kc.x + q0[j + 5] * kc.y + q0[j + 6] * kc.z + q0[j + 7] * kc.w;
                p1b += q1[j + 4] * kc.x + q1[j + 5] * kc.y + q1[j + 6] * kc.z + q1[j + 7] * kc.w;
            }
            float s0 = p0a + p0b, s1 = p1a + p1b;
            s0 += __shfl_xor(s0, 1); s0 += __shfl_xor(s0, 2);
            s1 += __shfl_xor(s1, 1); s1 += __shfl_xor(s1, 2);
            float p0 = __expf(s0 * 0.125f);
            float p1 = __expf(s1 * 0.125f);
            l0 += p0; l1 += p1;
            const float* vr = &Vs[kk][qd * 16];
#pragma unroll
            for (int j = 0; j < 16; j += 4) {
                float4 vv = *(const float4*)(vr + j);
                o0[j]     += p0 * vv.x; o0[j + 1] += p0 * vv.y;
                o0[j + 2] += p0 * vv.z; o0[j + 3] += p0 * vv.w;
                o1[j]     += p1 * vv.x; o1[j + 1] += p1 * vv.y;
                o1[j + 2] += p1 * vv.z; o1[j + 3] += p1 * vv.w;
            }
        }
    }
    float i0 = 1.f / l0, i1 = 1.f / l1;
#pragma unroll
    for (int j = 0; j < 16; j += 4) {
        *(float4*)(qrow0 + j) = make_float4(o0[j] * i0, o0[j + 1] * i0, o0[j + 2] * i0, o0[j + 3] * i0);
        *(float4*)(qrow1 + j) = make_float4(o1[j] * i1, o1[j + 1] * i1, o1[j + 2] * i1, o1[j + 3] * i1);
    }
}

// ---------- K3: attn_out = ctx @ out_w^T + out_b   (ld = 768 both sides) ----
// A = qkv q-slot (ctx), C = qkv k-slot. 64x64 tile, BK=16, 4x4 per thread.
__global__ __launch_bounds__(256) void k_lin_out(const float* __restrict__ A,
                                                 const float* __restrict__ W,
                                                 const float* __restrict__ bias,
                                                 float* __restrict__ C) {
    __shared__ float As[16][64];   // [k][m]
    __shared__ float Bs[16][64];   // [k][n]
    int tid = threadIdx.x;
    int tx = tid & 15, ty = tid >> 4;
    size_t m0 = (size_t)blockIdx.x * 64;
    int n0 = blockIdx.y * 64;
    int lrow = tid >> 2, lkp = (tid & 3) << 2;
    float acc[4][4] = {{0.f, 0.f, 0.f, 0.f}, {0.f, 0.f, 0.f, 0.f},
                       {0.f, 0.f, 0.f, 0.f}, {0.f, 0.f, 0.f, 0.f}};
    for (int k0 = 0; k0 < En; k0 += 16) {
        __syncthreads();
        float4 a = *(const float4*)(A + (m0 + lrow) * E3n + k0 + lkp);
        As[lkp + 0][lrow] = a.x; As[lkp + 1][lrow] = a.y;
        As[lkp + 2][lrow] = a.z; As[lkp + 3][lrow] = a.w;
        float4 wv = *(const float4*)(W + (size_t)(n0 + lrow) * En + k0 + lkp);
        Bs[lkp + 0][lrow] = wv.x; Bs[lkp + 1][lrow] = wv.y;
        Bs[lkp + 2][lrow] = wv.z; Bs[lkp + 3][lrow] = wv.w;
        __syncthreads();
#pragma unroll
        for (int k = 0; k < 16; ++k) {
            float4 av = *(const float4*)&As[k][ty * 4];
            float4 bv = *(const float4*)&Bs[k][tx * 4];
            acc[0][0] += av.x * bv.x; acc[0][1] += av.x * bv.y;
            acc[0][2] += av.x * bv.z; acc[0][3] += av.x * bv.w;
            acc[1][0] += av.y * bv.x; acc[1][1] += av.y * bv.y;
            acc[1][2] += av.y * bv.z; acc[1][3] += av.y * bv.w;
            acc[2][0] += av.z * bv.x; acc[2][1] += av.z * bv.y;
            acc[2][2] += av.z * bv.z; acc[2][3] += av.z * bv.w;
            acc[3][0] += av.w * bv.x; acc[3][1] += av.w * bv.y;
            acc[3][2] += av.w * bv.z; acc[3][3] += av.w * bv.w;
        }
    }
    float4 bb = *(const float4*)(bias + n0 + tx * 4);
#pragma unroll
    for (int i = 0; i < 4; ++i) {
        float* cp = C + (m0 + ty * 4 + i) * E3n + n0 + tx * 4;
        *(float4*)cp = make_float4(acc[i][0] + bb.x, acc[i][1] + bb.y,
                                   acc[i][2] + bb.z, acc[i][3] + bb.w);
    }
}

// ---------- K4: boundary MLP -> bscore[b,t] ----------
__global__ __launch_bounds__(256) void k_bscore(const float* __restrict__ ao,
                                                const float* __restrict__ w1,
                                                const float* __restrict__ b1,
                                                const float* __restrict__ w2,
                                                const float* __restrict__ b2,
                                                float* __restrict__ bsc) {
    __shared__ float w1s[32][257];
    __shared__ float as[8][En];
    int tid = threadIdx.x;
    for (int i = tid; i < 32 * En; i += 256) w1s[i >> 8][i & 255] = w1[i];
    int g = tid >> 5, j = tid & 31;
    float b1j = b1[j], w2j = w2[j], b2v = b2[0];
    int tok0 = blockIdx.x * 128;
    for (int r = 0; r < 16; ++r) {
        __syncthreads();
#pragma unroll
        for (int i = 0; i < 2; ++i) {
            int idx = tid + i * 256;               // 0..511
            int row = idx >> 6, pos = (idx & 63) << 2;
            *(float4*)&as[row][pos] =
                *(const float4*)(ao + (size_t)(tok0 + r * 8 + row) * E3n + pos);
        }
        __syncthreads();
        float ha = 0.f, hb = 0.f;
#pragma unroll
        for (int e = 0; e < En; e += 4) {
            float4 a = *(const float4*)&as[g][e];
            ha += a.x * w1s[j][e];     hb += a.y * w1s[j][e + 1];
            ha += a.z * w1s[j][e + 2]; hb += a.w * w1s[j][e + 3];
        }
        float hv = fmaxf(ha + hb + b1j, 0.f) * w2j;
        hv += __shfl_xor(hv, 16);
        hv += __shfl_xor(hv, 8);
        hv += __shfl_xor(hv, 4);
        hv += __shfl_xor(hv, 2);
        hv += __shfl_xor(hv, 1);
        if (j == 0) bsc[tok0 + r * 8 + g] = 1.f / (1.f + __expf(-(hv + b2v)));
    }
}

// ---------- K5: cumsum -> pid -> segment boundaries (pid monotone!) ----------
__global__ __launch_bounds__(1024) void k_scan(const float* __restrict__ bsc,
                                               int* __restrict__ segs) {
    __shared__ float wsum[16];
    __shared__ float s_pre[1024];
    __shared__ float s_tot;
    int b = blockIdx.x, t = threadIdx.x;
    float x = bsc[b * Tn + t];
#pragma unroll
    for (int d = 1; d < 64; d <<= 1) {
        float y = __shfl_up(x, d);
        if ((t & 63) >= d) x += y;
    }
    int w = t >> 6;
    if ((t & 63) == 63) wsum[w] = x;
    __syncthreads();
    if (t == 0) {
        float s = 0.f;
        for (int i = 0; i < 16; ++i) { float tmp = wsum[i]; wsum[i] = s; s += tmp; }
        s_tot = s;
    }
    __syncthreads();
    float pre = x + wsum[w];
    s_pre[t] = pre;
    __syncthreads();
    float denom = s_tot + 1e-6f;
    float qv = pre / denom * 32.0f;
    int pid = min((int)floorf(qv), 31);
    int pidprev = -1;
    if (t > 0) {
        float qp = s_pre[t - 1] / denom * 32.0f;
        pidprev = min((int)floorf(qp), 31);
    }
    for (int p = pidprev + 1; p <= pid; ++p) segs[b * 33 + p] = t;
    if (t == 1023)
        for (int p = pid + 1; p <= 32; ++p) segs[b * 33 + p] = Tn;
}

// ---------- K6: segment-mean pool + final linear ----------
__global__ __launch_bounds__(256) void k_pool_proj(const float* __restrict__ ao,
                                                   const int* __restrict__ segs,
                                                   const float* __restrict__ prw,
                                                   const float* __restrict__ prb,
                                                   float* __restrict__ out) {
    __shared__ float pes[En];
    int b = blockIdx.y, p = blockIdx.x;
    int s = segs[b * 33 + p];
    int e = segs[b * 33 + p + 1];
    int tid = threadIdx.x;
    float sum = 0.f;
    for (int t = s; t < e; ++t)
        sum += ao[((size_t)b * Tn + t) * E3n + tid];
    pes[tid] = sum / fmaxf((float)(e - s), 1.f);
    __syncthreads();
    float a0 = prb[tid], a1 = 0.f;
#pragma unroll
    for (int k = 0; k < En; k += 4) {
        float4 wv = *(const float4*)(prw + (size_t)tid * En + k);
        float4 pv = *(const float4*)&pes[k];
        a0 += wv.x * pv.x; a1 += wv.y * pv.y;
        a0 += wv.z * pv.z; a1 += wv.w * pv.w;
    }
    out[((size_t)b * Pn + p) * En + tid] = a0 + a1;
}

extern "C" void kernel_launch(void* const* d_in, const int* in_sizes, int n_in,
                              void* d_out, int out_size, void* d_ws, size_t ws_size,
                              hipStream_t stream) {
    const float* x    = (const float*)d_in[0];
    const float* ipw  = (const float*)d_in[1];
    const float* ipb  = (const float*)d_in[2];
    const float* inw  = (const float*)d_in[3];
    const float* inb  = (const float*)d_in[4];
    const float* outw = (const float*)d_in[5];
    const float* outb = (const float*)d_in[6];
    const float* bw1  = (const float*)d_in[7];
    const float* bb1  = (const float*)d_in[8];
    const float* bw2  = (const float*)d_in[9];
    const float* bb2  = (const float*)d_in[10];
    const float* prw  = (const float*)d_in[11];
    const float* prb  = (const float*)d_in[12];

    float* ws   = (float*)d_ws;
    float* Wc   = ws;                               // 24576 floats
    float* bc   = ws + 24576;                       // 768
    float* qkv  = ws + 25600;                       // 32768*768 floats
    float* bsc  = qkv + (size_t)32768 * 768;        // 32768
    int*   segs = (int*)(bsc + 32768);              // 32*33 ints

    k_comb_w<<<96, 256, 0, stream>>>(ipw, inw, Wc);
    k_comb_b<<<3, 256, 0, stream>>>(ipb, inw, inb, bc);
    k_qkv<<<dim3(3, 256), 256, 0, stream>>>(x, Wc, bc, qkv);
    k_attn<<<1024, 256, 0, stream>>>(qkv);
    // ctx now lives in the q-slot; write attn_out into the k-slot (ld 768)
    k_lin_out<<<dim3(512, 4), 256, 0, stream>>>(qkv, outw, outb, qkv + En);
    k_bscore<<<256, 256, 0, stream>>>(qkv + En, bw1, bb1, bw2, bb2, bsc);
    k_scan<<<32, 1024, 0, stream>>>(bsc, segs);
    k_pool_proj<<<dim3(32, 32), 256, 0, stream>>>(qkv + En, segs, prw, prb,
                                                  (float*)d_out);
}

// Round 3
// 340.453 us; speedup vs baseline: 3.1196x; 3.1196x over previous
//
#include <hip/hip_runtime.h>
#include <math.h>

constexpr int Bn  = 32;
constexpr int Tn  = 1024;
constexpr int INn = 32;
constexpr int En  = 256;
constexpr int HDn = 64;
constexpr int Pn  = 32;
constexpr int E3n = 768;

typedef short bf16x8 __attribute__((ext_vector_type(8)));
typedef float f32x4  __attribute__((ext_vector_type(4)));

__device__ __forceinline__ unsigned short f2bf(float f) {
    unsigned int b = __float_as_uint(f);
    b += 0x7FFF + ((b >> 16) & 1);          // RNE
    return (unsigned short)(b >> 16);
}

// ---------- K0a: W_comb[768,32] = in_proj_w[768,256] @ ip_w[256,32] ----------
__global__ __launch_bounds__(256) void k_comb_w(const float* __restrict__ ipw,
                                                const float* __restrict__ inw,
                                                float* __restrict__ Wc) {
    int idx = blockIdx.x * 256 + threadIdx.x;      // 24576 total
    int o = idx >> 5, i = idx & 31;
    const float* wr = inw + (size_t)o * En;
    float a0 = 0.f, a1 = 0.f;
    for (int e = 0; e < En; e += 2) {
        a0 += wr[e]     * ipw[(size_t)e * INn + i];
        a1 += wr[e + 1] * ipw[(size_t)(e + 1) * INn + i];
    }
    Wc[(size_t)o * INn + i] = a0 + a1;
}

// ---------- K0b: b_comb = in_proj_w @ ip_b + in_proj_b ----------
__global__ __launch_bounds__(256) void k_comb_b(const float* __restrict__ ipb,
                                                const float* __restrict__ inw,
                                                const float* __restrict__ inb,
                                                float* __restrict__ bc) {
    int o = blockIdx.x * 256 + threadIdx.x;        // 768 total
    const float* wr = inw + (size_t)o * En;
    float a = inb[o];
    for (int e = 0; e < En; ++e) a += wr[e] * ipb[e];
    bc[o] = a;
}

// ---------- K1: fused qkv projection ----------
// blockIdx.x = slot (0:Q fp32, 1:K bf16 [b,h,t,d], 2:V fp32)
__global__ __launch_bounds__(256) void k_qkv(const float* __restrict__ x,
                                             const float* __restrict__ Wc,
                                             const float* __restrict__ bc,
                                             float* __restrict__ Qf,
                                             unsigned short* __restrict__ Kb,
                                             float* __restrict__ Vf) {
    __shared__ float xs[128][INn];
    int tid = threadIdx.x;
    int col = blockIdx.x * 256 + tid;              // 0..767
    size_t row0 = (size_t)blockIdx.y * 128;
    float w[INn];
#pragma unroll
    for (int j = 0; j < INn; j += 4) {
        float4 t = *(const float4*)(Wc + (size_t)col * INn + j);
        w[j] = t.x; w[j + 1] = t.y; w[j + 2] = t.z; w[j + 3] = t.w;
    }
    float bias = bc[col];
    const float4* xv = (const float4*)(x + row0 * INn);
    float4* xsv = (float4*)&xs[0][0];
#pragma unroll
    for (int i = 0; i < 4; ++i) xsv[tid + i * 256] = xv[tid + i * 256];
    __syncthreads();
    if (blockIdx.x == 1) {                         // K slot -> bf16 [b,h,t,d]
        int h = tid >> 6, d = tid & 63;
        int b = (int)(row0 >> 10), t0 = (int)(row0 & 1023);
        unsigned short* outk = Kb + (((size_t)(b * 4 + h)) * 1024 + t0) * 64 + d;
#pragma unroll 2
        for (int m = 0; m < 128; ++m) {
            float a0 = bias, a1 = 0.f;
#pragma unroll
            for (int j = 0; j < INn; j += 4) {
                float4 t = *(const float4*)&xs[m][j];
                a0 += t.x * w[j];     a1 += t.y * w[j + 1];
                a0 += t.z * w[j + 2]; a1 += t.w * w[j + 3];
            }
            outk[(size_t)m * 64] = f2bf(a0 + a1);
        }
    } else {                                       // Q or V -> fp32 [t,256]
        float* outp = (blockIdx.x ? Vf : Qf) + row0 * En + tid;
#pragma unroll 2
        for (int m = 0; m < 128; ++m) {
            float a0 = bias, a1 = 0.f;
#pragma unroll
            for (int j = 0; j < INn; j += 4) {
                float4 t = *(const float4*)&xs[m][j];
                a0 += t.x * w[j];     a1 += t.y * w[j + 1];
                a0 += t.z * w[j + 2]; a1 += t.w * w[j + 3];
            }
            outp[(size_t)m * En] = a0 + a1;
        }
    }
}

// ---------- K1b: V transpose -> Vt bf16 [b,h,d,t] ----------
// grid = 128 (b*h) * 16 (t-tiles of 64) = 2048 blocks  [bugfix: was 512]
__global__ __launch_bounds__(256) void k_vt(const float* __restrict__ Vf,
                                            unsigned short* __restrict__ Vt) {
    __shared__ float ls[64][65];
    int bh = blockIdx.x >> 4;                      // b*4+h, 0..127
    int t0 = (blockIdx.x & 15) * 64;
    int b = bh >> 2, h = bh & 3;
    int tid = threadIdx.x;
#pragma unroll
    for (int r = 0; r < 2; ++r) {
        int idx = r * 256 + tid; int tt = idx >> 3, d8 = idx & 7;
        const float* s = Vf + ((size_t)(b * 1024 + t0 + tt)) * En + h * 64 + d8 * 8;
        float4 a = *(const float4*)s, c = *(const float4*)(s + 4);
        float* d = &ls[tt][d8 * 8];
        d[0] = a.x; d[1] = a.y; d[2] = a.z; d[3] = a.w;
        d[4] = c.x; d[5] = c.y; d[6] = c.z; d[7] = c.w;
    }
    __syncthreads();
#pragma unroll
    for (int r = 0; r < 2; ++r) {
        int idx = r * 256 + tid; int dd = idx >> 3, t8 = idx & 7;
        unsigned int u0 = f2bf(ls[t8 * 8 + 0][dd]) | (f2bf(ls[t8 * 8 + 1][dd]) << 16);
        unsigned int u1 = f2bf(ls[t8 * 8 + 2][dd]) | (f2bf(ls[t8 * 8 + 3][dd]) << 16);
        unsigned int u2 = f2bf(ls[t8 * 8 + 4][dd]) | (f2bf(ls[t8 * 8 + 5][dd]) << 16);
        unsigned int u3 = f2bf(ls[t8 * 8 + 6][dd]) | (f2bf(ls[t8 * 8 + 7][dd]) << 16);
        *(uint4*)(Vt + ((size_t)(bh * 64 + dd)) * 1024 + t0 + t8 * 8) =
            make_uint4(u0, u1, u2, u3);
    }
}

// ---------- K2: MFMA flash attention ----------
// grid 1024: bh = blk & 127 (L2 locality per XCD), qb = blk >> 7.
// wave handles 2 q-tiles of 16 (32 q rows); workgroup = 128 q rows.
__global__ __launch_bounds__(256, 4) void k_attn(const float* __restrict__ Qf,
                                                 const unsigned short* __restrict__ Kb,
                                                 const unsigned short* __restrict__ Vt,
                                                 float* __restrict__ Ctx) {
    __shared__ unsigned short Ks[64][72];
    __shared__ unsigned short Vs[64][72];
    __shared__ __align__(16) unsigned short Pl[4][2][16][40];
    int blk = blockIdx.x;
    int bh = blk & 127, qb = blk >> 7;
    int b = bh >> 2, h = bh & 3;
    int tid = threadIdx.x;
    int wv = tid >> 6, lane = tid & 63;
    int cl = lane & 15, quad = lane >> 4;
    int qbase = qb * 128 + wv * 32;

    f32x4 zero4 = {0.f, 0.f, 0.f, 0.f};
    bf16x8 qfrag[2][2];
#pragma unroll
    for (int t = 0; t < 2; ++t)
#pragma unroll
        for (int ch = 0; ch < 2; ++ch) {
            const float* qs = Qf + ((size_t)(b * 1024 + qbase + t * 16 + cl)) * En +
                              h * 64 + ch * 32 + quad * 8;
            float4 a = *(const float4*)qs, c = *(const float4*)(qs + 4);
            bf16x8 q;
            q[0] = (short)f2bf(a.x); q[1] = (short)f2bf(a.y);
            q[2] = (short)f2bf(a.z); q[3] = (short)f2bf(a.w);
            q[4] = (short)f2bf(c.x); q[5] = (short)f2bf(c.y);
            q[6] = (short)f2bf(c.z); q[7] = (short)f2bf(c.w);
            qfrag[t][ch] = q;
        }
    f32x4 acc[2][4];
#pragma unroll
    for (int t = 0; t < 2; ++t)
#pragma unroll
        for (int dt = 0; dt < 4; ++dt) acc[t][dt] = zero4;
    float l[2] = {0.f, 0.f};

    const unsigned short* Kbase = Kb + (size_t)bh * 1024 * 64;
    const unsigned short* Vbase = Vt + (size_t)bh * 64 * 1024;

    for (int kt = 0; kt < 16; ++kt) {
#pragma unroll
        for (int r = 0; r < 2; ++r) {
            int idx = r * 256 + tid; int row = idx >> 3, c16 = idx & 7;
            *(uint4*)&Ks[row][c16 * 8] =
                *(const uint4*)(Kbase + (size_t)(kt * 64 + row) * 64 + c16 * 8);
            *(uint4*)&Vs[row][c16 * 8] =
                *(const uint4*)(Vbase + (size_t)row * 1024 + kt * 64 + c16 * 8);
        }
        __syncthreads();
#pragma unroll
        for (int c = 0; c < 2; ++c) {
            bf16x8 ka0 = *(const bf16x8*)&Ks[c * 32 + cl][quad * 8];
            bf16x8 ka1 = *(const bf16x8*)&Ks[c * 32 + cl][32 + quad * 8];
            bf16x8 kb0 = *(const bf16x8*)&Ks[c * 32 + 16 + cl][quad * 8];
            bf16x8 kb1 = *(const bf16x8*)&Ks[c * 32 + 16 + cl][32 + quad * 8];
#pragma unroll
            for (int t = 0; t < 2; ++t) {
                f32x4 s0 = __builtin_amdgcn_mfma_f32_16x16x32_bf16(ka0, qfrag[t][0], zero4, 0, 0, 0);
                s0 = __builtin_amdgcn_mfma_f32_16x16x32_bf16(ka1, qfrag[t][1], s0, 0, 0, 0);
                f32x4 s1 = __builtin_amdgcn_mfma_f32_16x16x32_bf16(kb0, qfrag[t][0], zero4, 0, 0, 0);
                s1 = __builtin_amdgcn_mfma_f32_16x16x32_bf16(kb1, qfrag[t][1], s1, 0, 0, 0);
                float p0 = __expf(0.125f * s0[0]), p1 = __expf(0.125f * s0[1]);
                float p2 = __expf(0.125f * s0[2]), p3 = __expf(0.125f * s0[3]);
                float p4 = __expf(0.125f * s1[0]), p5 = __expf(0.125f * s1[1]);
                float p6 = __expf(0.125f * s1[2]), p7 = __expf(0.125f * s1[3]);
                l[t] += ((p0 + p1) + (p2 + p3)) + ((p4 + p5) + (p6 + p7));
                unsigned int w0 = f2bf(p0) | ((unsigned int)f2bf(p1) << 16);
                unsigned int w1 = f2bf(p2) | ((unsigned int)f2bf(p3) << 16);
                unsigned int w2 = f2bf(p4) | ((unsigned int)f2bf(p5) << 16);
                unsigned int w3 = f2bf(p6) | ((unsigned int)f2bf(p7) << 16);
                *(unsigned int*)&Pl[wv][t][cl][quad * 4]          = w0;
                *(unsigned int*)&Pl[wv][t][cl][quad * 4 + 2]      = w1;
                *(unsigned int*)&Pl[wv][t][cl][16 + quad * 4]     = w2;
                *(unsigned int*)&Pl[wv][t][cl][16 + quad * 4 + 2] = w3;
            }
            asm volatile("s_waitcnt lgkmcnt(0)" ::: "memory");
            bf16x8 va[4];
#pragma unroll
            for (int dt = 0; dt < 4; ++dt)
                va[dt] = *(const bf16x8*)&Vs[dt * 16 + cl][c * 32 + quad * 8];
#pragma unroll
            for (int t = 0; t < 2; ++t) {
                bf16x8 pf = *(const bf16x8*)&Pl[wv][t][cl][quad * 8];
#pragma unroll
                for (int dt = 0; dt < 4; ++dt)
                    acc[t][dt] = __builtin_amdgcn_mfma_f32_16x16x32_bf16(pf, va[dt], acc[t][dt], 0, 0, 0);
            }
        }
        __syncthreads();
    }
    // normalize + store (ctx into Qf q area: race-free, own rows/cols only)
#pragma unroll
    for (int t = 0; t < 2; ++t) {
        l[t] += __shfl_xor(l[t], 16);
        l[t] += __shfl_xor(l[t], 32);
    }
    float inv0 = 1.f / l[0], inv1 = 1.f / l[1];
#pragma unroll
    for (int t = 0; t < 2; ++t) {
        float invt = t ? inv1 : inv0;
#pragma unroll
        for (int r = 0; r < 4; ++r) {
            float rl = __shfl(invt, quad * 4 + r);
#pragma unroll
            for (int dt = 0; dt < 4; ++dt) {
                Ctx[((size_t)(b * 1024 + qbase + t * 16 + quad * 4 + r)) * En +
                    h * 64 + dt * 16 + cl] = acc[t][dt][r] * rl;
            }
        }
    }
}

// ---------- K3: attn_out = ctx @ out_w^T + out_b   (ld = 256 both sides) ----
__global__ __launch_bounds__(256) void k_lin_out(const float* __restrict__ A,
                                                 const float* __restrict__ W,
                                                 const float* __restrict__ bias,
                                                 float* __restrict__ C) {
    __shared__ float As[16][64];   // [k][m]
    __shared__ float Bs[16][64];   // [k][n]
    int tid = threadIdx.x;
    int tx = tid & 15, ty = tid >> 4;
    size_t m0 = (size_t)blockIdx.x * 64;
    int n0 = blockIdx.y * 64;
    int lrow = tid >> 2, lkp = (tid & 3) << 2;
    float acc[4][4] = {{0.f, 0.f, 0.f, 0.f}, {0.f, 0.f, 0.f, 0.f},
                       {0.f, 0.f, 0.f, 0.f}, {0.f, 0.f, 0.f, 0.f}};
    for (int k0 = 0; k0 < En; k0 += 16) {
        __syncthreads();
        float4 a = *(const float4*)(A + (m0 + lrow) * En + k0 + lkp);
        As[lkp + 0][lrow] = a.x; As[lkp + 1][lrow] = a.y;
        As[lkp + 2][lrow] = a.z; As[lkp + 3][lrow] = a.w;
        float4 wv = *(const float4*)(W + (size_t)(n0 + lrow) * En + k0 + lkp);
        Bs[lkp + 0][lrow] = wv.x; Bs[lkp + 1][lrow] = wv.y;
        Bs[lkp + 2][lrow] = wv.z; Bs[lkp + 3][lrow] = wv.w;
        __syncthreads();
#pragma unroll
        for (int k = 0; k < 16; ++k) {
            float4 av = *(const float4*)&As[k][ty * 4];
            float4 bv = *(const float4*)&Bs[k][tx * 4];
            acc[0][0] += av.x * bv.x; acc[0][1] += av.x * bv.y;
            acc[0][2] += av.x * bv.z; acc[0][3] += av.x * bv.w;
            acc[1][0] += av.y * bv.x; acc[1][1] += av.y * bv.y;
            acc[1][2] += av.y * bv.z; acc[1][3] += av.y * bv.w;
            acc[2][0] += av.z * bv.x; acc[2][1] += av.z * bv.y;
            acc[2][2] += av.z * bv.z; acc[2][3] += av.z * bv.w;
            acc[3][0] += av.w * bv.x; acc[3][1] += av.w * bv.y;
            acc[3][2] += av.w * bv.z; acc[3][3] += av.w * bv.w;
        }
    }
    float4 bb = *(const float4*)(bias + n0 + tx * 4);
#pragma unroll
    for (int i = 0; i < 4; ++i) {
        float* cp = C + (m0 + ty * 4 + i) * En + n0 + tx * 4;
        *(float4*)cp = make_float4(acc[i][0] + bb.x, acc[i][1] + bb.y,
                                   acc[i][2] + bb.z, acc[i][3] + bb.w);
    }
}

// ---------- K4: boundary MLP -> bscore[b,t] ----------
__global__ __launch_bounds__(256) void k_bscore(const float* __restrict__ ao,
                                                const float* __restrict__ w1,
                                                const float* __restrict__ b1,
                                                const float* __restrict__ w2,
                                                const float* __restrict__ b2,
                                                float* __restrict__ bsc) {
    __shared__ float w1s[32][257];
    __shared__ float as[8][En];
    int tid = threadIdx.x;
    for (int i = tid; i < 32 * En; i += 256) w1s[i >> 8][i & 255] = w1[i];
    int g = tid >> 5, j = tid & 31;
    float b1j = b1[j], w2j = w2[j], b2v = b2[0];
    int tok0 = blockIdx.x * 128;
    for (int r = 0; r < 16; ++r) {
        __syncthreads();
#pragma unroll
        for (int i = 0; i < 2; ++i) {
            int idx = tid + i * 256;               // 0..511
            int row = idx >> 6, pos = (idx & 63) << 2;
            *(float4*)&as[row][pos] =
                *(const float4*)(ao + (size_t)(tok0 + r * 8 + row) * En + pos);
        }
        __syncthreads();
        float ha = 0.f, hb = 0.f;
#pragma unroll
        for (int e = 0; e < En; e += 4) {
            float4 a = *(const float4*)&as[g][e];
            ha += a.x * w1s[j][e];     hb += a.y * w1s[j][e + 1];
            ha += a.z * w1s[j][e + 2]; hb += a.w * w1s[j][e + 3];
        }
        float hv = fmaxf(ha + hb + b1j, 0.f) * w2j;
        hv += __shfl_xor(hv, 16);
        hv += __shfl_xor(hv, 8);
        hv += __shfl_xor(hv, 4);
        hv += __shfl_xor(hv, 2);
        hv += __shfl_xor(hv, 1);
        if (j == 0) bsc[tok0 + r * 8 + g] = 1.f / (1.f + __expf(-(hv + b2v)));
    }
}

// ---------- K5: cumsum -> pid -> segment boundaries (pid monotone!) ----------
__global__ __launch_bounds__(1024) void k_scan(const float* __restrict__ bsc,
                                               int* __restrict__ segs) {
    __shared__ float wsum[16];
    __shared__ float s_pre[1024];
    __shared__ float s_tot;
    int b = blockIdx.x, t = threadIdx.x;
    float x = bsc[b * Tn + t];
#pragma unroll
    for (int d = 1; d < 64; d <<= 1) {
        float y = __shfl_up(x, d);
        if ((t & 63) >= d) x += y;
    }
    int w = t >> 6;
    if ((t & 63) == 63) wsum[w] = x;
    __syncthreads();
    if (t == 0) {
        float s = 0.f;
        for (int i = 0; i < 16; ++i) { float tmp = wsum[i]; wsum[i] = s; s += tmp; }
        s_tot = s;
    }
    __syncthreads();
    float pre = x + wsum[w];
    s_pre[t] = pre;
    __syncthreads();
    float denom = s_tot + 1e-6f;
    float qv = pre / denom * 32.0f;
    int pid = min((int)floorf(qv), 31);
    int pidprev = -1;
    if (t > 0) {
        float qp = s_pre[t - 1] / denom * 32.0f;
        pidprev = min((int)floorf(qp), 31);
    }
    for (int p = pidprev + 1; p <= pid; ++p) segs[b * 33 + p] = t;
    if (t == 1023)
        for (int p = pid + 1; p <= 32; ++p) segs[b * 33 + p] = Tn;
}

// ---------- K6: segment-mean pool + final linear ----------
__global__ __launch_bounds__(256) void k_pool_proj(const float* __restrict__ ao,
                                                   const int* __restrict__ segs,
                                                   const float* __restrict__ prw,
                                                   const float* __restrict__ prb,
                                                   float* __restrict__ out) {
    __shared__ float pes[En];
    int b = blockIdx.y, p = blockIdx.x;
    int s = segs[b * 33 + p];
    int e = segs[b * 33 + p + 1];
    int tid = threadIdx.x;
    float sum = 0.f;
    for (int t = s; t < e; ++t)
        sum += ao[((size_t)b * Tn + t) * En + tid];
    pes[tid] = sum / fmaxf((float)(e - s), 1.f);
    __syncthreads();
    float a0 = prb[tid], a1 = 0.f;
#pragma unroll
    for (int k = 0; k < En; k += 4) {
        float4 wv = *(const float4*)(prw + (size_t)tid * En + k);
        float4 pv = *(const float4*)&pes[k];
        a0 += wv.x * pv.x; a1 += wv.y * pv.y;
        a0 += wv.z * pv.z; a1 += wv.w * pv.w;
    }
    out[((size_t)b * Pn + p) * En + tid] = a0 + a1;
}

extern "C" void kernel_launch(void* const* d_in, const int* in_sizes, int n_in,
                              void* d_out, int out_size, void* d_ws, size_t ws_size,
                              hipStream_t stream) {
    const float* x    = (const float*)d_in[0];
    const float* ipw  = (const float*)d_in[1];
    const float* ipb  = (const float*)d_in[2];
    const float* inw  = (const float*)d_in[3];
    const float* inb  = (const float*)d_in[4];
    const float* outw = (const float*)d_in[5];
    const float* outb = (const float*)d_in[6];
    const float* bw1  = (const float*)d_in[7];
    const float* bb1  = (const float*)d_in[8];
    const float* bw2  = (const float*)d_in[9];
    const float* bb2  = (const float*)d_in[10];
    const float* prw  = (const float*)d_in[11];
    const float* prb  = (const float*)d_in[12];

    float* Qf = (float*)d_ws;                                   // 32768*256 f32
    unsigned short* Kb = (unsigned short*)(Qf + (size_t)32768 * 256);  // 8.4M bf16
    unsigned short* Vt = Kb + (size_t)8388608;                  // 8.4M bf16
    float* Vf = (float*)(Vt + (size_t)8388608);                 // 32768*256 f32 (later attn_out)
    float* Wc = Vf + (size_t)32768 * 256;                       // 24576
    float* bc = Wc + 24576;                                     // 768
    float* bsc = bc + 768;                                      // 32768
    int* segs = (int*)(bsc + 32768);                            // 32*33

    k_comb_w<<<96, 256, 0, stream>>>(ipw, inw, Wc);
    k_comb_b<<<3, 256, 0, stream>>>(ipb, inw, inb, bc);
    k_qkv<<<dim3(3, 256), 256, 0, stream>>>(x, Wc, bc, Qf, Kb, Vf);
    k_vt<<<2048, 256, 0, stream>>>(Vf, Vt);
    k_attn<<<1024, 256, 0, stream>>>(Qf, Kb, Vt, Qf);
    // attn_out into Vf (V no longer needed)
    k_lin_out<<<dim3(512, 4), 256, 0, stream>>>(Qf, outw, outb, Vf);
    k_bscore<<<256, 256, 0, stream>>>(Vf, bw1, bb1, bw2, bb2, bsc);
    k_scan<<<32, 1024, 0, stream>>>(bsc, segs);
    k_pool_proj<<<dim3(32, 32), 256, 0, stream>>>(Vf, segs, prw, prb,
                                                  (float*)d_out);
}

// Round 4
// 306.534 us; speedup vs baseline: 3.4648x; 1.1107x over previous
//
#include <hip/hip_runtime.h>
#include <math.h>

constexpr int Bn  = 32;
constexpr int Tn  = 1024;
constexpr int INn = 32;
constexpr int En  = 256;
constexpr int HDn = 64;
constexpr int Pn  = 32;
constexpr int E3n = 768;

typedef short bf16x8 __attribute__((ext_vector_type(8)));
typedef float f32x4  __attribute__((ext_vector_type(4)));

__device__ __forceinline__ unsigned short f2bf(float f) {
    unsigned int b = __float_as_uint(f);
    b += 0x7FFF + ((b >> 16) & 1);          // RNE
    return (unsigned short)(b >> 16);
}

// ---------- K0a: W_comb[768,32] = in_proj_w[768,256] @ ip_w[256,32] ----------
__global__ __launch_bounds__(256) void k_comb_w(const float* __restrict__ ipw,
                                                const float* __restrict__ inw,
                                                float* __restrict__ Wc) {
    int idx = blockIdx.x * 256 + threadIdx.x;      // 24576 total
    int o = idx >> 5, i = idx & 31;
    const float* wr = inw + (size_t)o * En;
    float a0 = 0.f, a1 = 0.f;
    for (int e = 0; e < En; e += 2) {
        a0 += wr[e]     * ipw[(size_t)e * INn + i];
        a1 += wr[e + 1] * ipw[(size_t)(e + 1) * INn + i];
    }
    Wc[(size_t)o * INn + i] = a0 + a1;
}

// ---------- K0b: b_comb = in_proj_w @ ip_b + in_proj_b ----------
__global__ __launch_bounds__(256) void k_comb_b(const float* __restrict__ ipb,
                                                const float* __restrict__ inw,
                                                const float* __restrict__ inb,
                                                float* __restrict__ bc) {
    int o = blockIdx.x * 256 + threadIdx.x;        // 768 total
    const float* wr = inw + (size_t)o * En;
    float a = inb[o];
    for (int e = 0; e < En; ++e) a += wr[e] * ipb[e];
    bc[o] = a;
}

// ---------- K0c: out_w fp32 [256][256] -> bf16 (same layout) ----------
__global__ __launch_bounds__(256) void k_wcvt(const float* __restrict__ w,
                                              unsigned short* __restrict__ wb) {
    int idx = blockIdx.x * 256 + threadIdx.x;      // 16384 float4s
    float4 a = *(const float4*)(w + (size_t)idx * 4);
    unsigned int u0 = f2bf(a.x) | ((unsigned int)f2bf(a.y) << 16);
    unsigned int u1 = f2bf(a.z) | ((unsigned int)f2bf(a.w) << 16);
    *(uint2*)(wb + (size_t)idx * 4) = make_uint2(u0, u1);
}

// ---------- K1: fused qkv projection ----------
// blockIdx.x = slot (0:Q bf16 [b,h,t,d], 1:K bf16 [b,h,t,d], 2:V fp32 [t,256])
__global__ __launch_bounds__(256) void k_qkv(const float* __restrict__ x,
                                             const float* __restrict__ Wc,
                                             const float* __restrict__ bc,
                                             unsigned short* __restrict__ Qb,
                                             unsigned short* __restrict__ Kb,
                                             float* __restrict__ Vf) {
    __shared__ float xs[128][INn];
    int tid = threadIdx.x;
    int col = blockIdx.x * 256 + tid;              // 0..767
    size_t row0 = (size_t)blockIdx.y * 128;
    float w[INn];
#pragma unroll
    for (int j = 0; j < INn; j += 4) {
        float4 t = *(const float4*)(Wc + (size_t)col * INn + j);
        w[j] = t.x; w[j + 1] = t.y; w[j + 2] = t.z; w[j + 3] = t.w;
    }
    float bias = bc[col];
    const float4* xv = (const float4*)(x + row0 * INn);
    float4* xsv = (float4*)&xs[0][0];
#pragma unroll
    for (int i = 0; i < 4; ++i) xsv[tid + i * 256] = xv[tid + i * 256];
    __syncthreads();
    if (blockIdx.x <= 1) {                         // Q or K -> bf16 [b,h,t,d]
        int h = tid >> 6, d = tid & 63;
        int b = (int)(row0 >> 10), t0 = (int)(row0 & 1023);
        unsigned short* outk = (blockIdx.x ? Kb : Qb) +
                               (((size_t)(b * 4 + h)) * 1024 + t0) * 64 + d;
#pragma unroll 2
        for (int m = 0; m < 128; ++m) {
            float a0 = bias, a1 = 0.f;
#pragma unroll
            for (int j = 0; j < INn; j += 4) {
                float4 t = *(const float4*)&xs[m][j];
                a0 += t.x * w[j];     a1 += t.y * w[j + 1];
                a0 += t.z * w[j + 2]; a1 += t.w * w[j + 3];
            }
            outk[(size_t)m * 64] = f2bf(a0 + a1);
        }
    } else {                                       // V -> fp32 [t,256]
        float* outp = Vf + row0 * En + tid;
#pragma unroll 2
        for (int m = 0; m < 128; ++m) {
            float a0 = bias, a1 = 0.f;
#pragma unroll
            for (int j = 0; j < INn; j += 4) {
                float4 t = *(const float4*)&xs[m][j];
                a0 += t.x * w[j];     a1 += t.y * w[j + 1];
                a0 += t.z * w[j + 2]; a1 += t.w * w[j + 3];
            }
            outp[(size_t)m * En] = a0 + a1;
        }
    }
}

// ---------- K1b: V transpose -> Vt bf16 [b,h,d,t]  (grid 2048) ----------
__global__ __launch_bounds__(256) void k_vt(const float* __restrict__ Vf,
                                            unsigned short* __restrict__ Vt) {
    __shared__ float ls[64][65];
    int bh = blockIdx.x >> 4;                      // b*4+h, 0..127
    int t0 = (blockIdx.x & 15) * 64;
    int b = bh >> 2, h = bh & 3;
    int tid = threadIdx.x;
#pragma unroll
    for (int r = 0; r < 2; ++r) {
        int idx = r * 256 + tid; int tt = idx >> 3, d8 = idx & 7;
        const float* s = Vf + ((size_t)(b * 1024 + t0 + tt)) * En + h * 64 + d8 * 8;
        float4 a = *(const float4*)s, c = *(const float4*)(s + 4);
        float* d = &ls[tt][d8 * 8];
        d[0] = a.x; d[1] = a.y; d[2] = a.z; d[3] = a.w;
        d[4] = c.x; d[5] = c.y; d[6] = c.z; d[7] = c.w;
    }
    __syncthreads();
#pragma unroll
    for (int r = 0; r < 2; ++r) {
        int idx = r * 256 + tid; int dd = idx >> 3, t8 = idx & 7;
        unsigned int u0 = f2bf(ls[t8 * 8 + 0][dd]) | (f2bf(ls[t8 * 8 + 1][dd]) << 16);
        unsigned int u1 = f2bf(ls[t8 * 8 + 2][dd]) | (f2bf(ls[t8 * 8 + 3][dd]) << 16);
        unsigned int u2 = f2bf(ls[t8 * 8 + 4][dd]) | (f2bf(ls[t8 * 8 + 5][dd]) << 16);
        unsigned int u3 = f2bf(ls[t8 * 8 + 6][dd]) | (f2bf(ls[t8 * 8 + 7][dd]) << 16);
        *(uint4*)(Vt + ((size_t)(bh * 64 + dd)) * 1024 + t0 + t8 * 8) =
            make_uint4(u0, u1, u2, u3);
    }
}

// ---------- K2: MFMA flash attention ----------
__global__ __launch_bounds__(256, 4) void k_attn(const unsigned short* __restrict__ Qb,
                                                 const unsigned short* __restrict__ Kb,
                                                 const unsigned short* __restrict__ Vt,
                                                 float* __restrict__ Ctx) {
    __shared__ unsigned short Ks[64][72];
    __shared__ unsigned short Vs[64][72];
    __shared__ __align__(16) unsigned short Pl[4][2][16][40];
    int blk = blockIdx.x;
    int bh = blk & 127, qb = blk >> 7;
    int b = bh >> 2, h = bh & 3;
    int tid = threadIdx.x;
    int wv = tid >> 6, lane = tid & 63;
    int cl = lane & 15, quad = lane >> 4;
    int qbase = qb * 128 + wv * 32;

    f32x4 zero4 = {0.f, 0.f, 0.f, 0.f};
    bf16x8 qfrag[2][2];
#pragma unroll
    for (int t = 0; t < 2; ++t)
#pragma unroll
        for (int ch = 0; ch < 2; ++ch)
            qfrag[t][ch] = *(const bf16x8*)(Qb +
                ((size_t)bh * 1024 + qbase + t * 16 + cl) * 64 + ch * 32 + quad * 8);
    f32x4 acc[2][4];
#pragma unroll
    for (int t = 0; t < 2; ++t)
#pragma unroll
        for (int dt = 0; dt < 4; ++dt) acc[t][dt] = zero4;
    float l[2] = {0.f, 0.f};

    const unsigned short* Kbase = Kb + (size_t)bh * 1024 * 64;
    const unsigned short* Vbase = Vt + (size_t)bh * 64 * 1024;

    for (int kt = 0; kt < 16; ++kt) {
#pragma unroll
        for (int r = 0; r < 2; ++r) {
            int idx = r * 256 + tid; int row = idx >> 3, c16 = idx & 7;
            *(uint4*)&Ks[row][c16 * 8] =
                *(const uint4*)(Kbase + (size_t)(kt * 64 + row) * 64 + c16 * 8);
            *(uint4*)&Vs[row][c16 * 8] =
                *(const uint4*)(Vbase + (size_t)row * 1024 + kt * 64 + c16 * 8);
        }
        __syncthreads();
#pragma unroll
        for (int c = 0; c < 2; ++c) {
            bf16x8 ka0 = *(const bf16x8*)&Ks[c * 32 + cl][quad * 8];
            bf16x8 ka1 = *(const bf16x8*)&Ks[c * 32 + cl][32 + quad * 8];
            bf16x8 kb0 = *(const bf16x8*)&Ks[c * 32 + 16 + cl][quad * 8];
            bf16x8 kb1 = *(const bf16x8*)&Ks[c * 32 + 16 + cl][32 + quad * 8];
#pragma unroll
            for (int t = 0; t < 2; ++t) {
                f32x4 s0 = __builtin_amdgcn_mfma_f32_16x16x32_bf16(ka0, qfrag[t][0], zero4, 0, 0, 0);
                s0 = __builtin_amdgcn_mfma_f32_16x16x32_bf16(ka1, qfrag[t][1], s0, 0, 0, 0);
                f32x4 s1 = __builtin_amdgcn_mfma_f32_16x16x32_bf16(kb0, qfrag[t][0], zero4, 0, 0, 0);
                s1 = __builtin_amdgcn_mfma_f32_16x16x32_bf16(kb1, qfrag[t][1], s1, 0, 0, 0);
                float p0 = __expf(0.125f * s0[0]), p1 = __expf(0.125f * s0[1]);
                float p2 = __expf(0.125f * s0[2]), p3 = __expf(0.125f * s0[3]);
                float p4 = __expf(0.125f * s1[0]), p5 = __expf(0.125f * s1[1]);
                float p6 = __expf(0.125f * s1[2]), p7 = __expf(0.125f * s1[3]);
                l[t] += ((p0 + p1) + (p2 + p3)) + ((p4 + p5) + (p6 + p7));
                unsigned int w0 = f2bf(p0) | ((unsigned int)f2bf(p1) << 16);
                unsigned int w1 = f2bf(p2) | ((unsigned int)f2bf(p3) << 16);
                unsigned int w2 = f2bf(p4) | ((unsigned int)f2bf(p5) << 16);
                unsigned int w3 = f2bf(p6) | ((unsigned int)f2bf(p7) << 16);
                *(unsigned int*)&Pl[wv][t][cl][quad * 4]          = w0;
                *(unsigned int*)&Pl[wv][t][cl][quad * 4 + 2]      = w1;
                *(unsigned int*)&Pl[wv][t][cl][16 + quad * 4]     = w2;
                *(unsigned int*)&Pl[wv][t][cl][16 + quad * 4 + 2] = w3;
            }
            asm volatile("s_waitcnt lgkmcnt(0)" ::: "memory");
            bf16x8 va[4];
#pragma unroll
            for (int dt = 0; dt < 4; ++dt)
                va[dt] = *(const bf16x8*)&Vs[dt * 16 + cl][c * 32 + quad * 8];
#pragma unroll
            for (int t = 0; t < 2; ++t) {
                bf16x8 pf = *(const bf16x8*)&Pl[wv][t][cl][quad * 8];
#pragma unroll
                for (int dt = 0; dt < 4; ++dt)
                    acc[t][dt] = __builtin_amdgcn_mfma_f32_16x16x32_bf16(pf, va[dt], acc[t][dt], 0, 0, 0);
            }
        }
        __syncthreads();
    }
#pragma unroll
    for (int t = 0; t < 2; ++t) {
        l[t] += __shfl_xor(l[t], 16);
        l[t] += __shfl_xor(l[t], 32);
    }
    float inv0 = 1.f / l[0], inv1 = 1.f / l[1];
#pragma unroll
    for (int t = 0; t < 2; ++t) {
        float invt = t ? inv1 : inv0;
#pragma unroll
        for (int r = 0; r < 4; ++r) {
            float rl = __shfl(invt, quad * 4 + r);
#pragma unroll
            for (int dt = 0; dt < 4; ++dt) {
                Ctx[((size_t)(b * 1024 + qbase + t * 16 + quad * 4 + r)) * En +
                    h * 64 + dt * 16 + cl] = acc[t][dt][r] * rl;
            }
        }
    }
}

// ---------- K3: attn_out = ctx @ out_w^T + out_b  via bf16 MFMA ----------
// grid 512 (m-tiles of 64). BM=64, BN=256 (wave owns 64 n), BK=32, K=256.
__global__ __launch_bounds__(256) void k_out_mfma(const float* __restrict__ Ctx,
                                                  const unsigned short* __restrict__ Wb,
                                                  const float* __restrict__ bias,
                                                  float* __restrict__ AO) {
    __shared__ unsigned short As[64][32];   // [m][k]
    __shared__ unsigned short Bs[256][32];  // [n][k]
    int tid = threadIdx.x;
    int wv = tid >> 6, lane = tid & 63;
    int cl = lane & 15, quad = lane >> 4;
    size_t m0 = (size_t)blockIdx.x * 64;

    f32x4 acc[4][4];
#pragma unroll
    for (int mt = 0; mt < 4; ++mt)
#pragma unroll
        for (int nt = 0; nt < 4; ++nt) acc[mt][nt] = {0.f, 0.f, 0.f, 0.f};

    for (int kt = 0; kt < 8; ++kt) {
        if (kt) __syncthreads();
        // stage A: 64x32 fp32 -> bf16
#pragma unroll
        for (int j = 0; j < 2; ++j) {
            int lin = j * 256 + tid;               // 0..511
            int row = lin >> 3, c4 = lin & 7;
            float4 a = *(const float4*)(Ctx + (m0 + row) * En + kt * 32 + c4 * 4);
            unsigned int u0 = f2bf(a.x) | ((unsigned int)f2bf(a.y) << 16);
            unsigned int u1 = f2bf(a.z) | ((unsigned int)f2bf(a.w) << 16);
            *(uint2*)&As[row][c4 * 4] = make_uint2(u0, u1);
        }
        // stage B: 256x32 bf16
#pragma unroll
        for (int j = 0; j < 4; ++j) {
            int lin = j * 256 + tid;               // 0..1023
            int n = lin >> 2, c = lin & 3;
            *(uint4*)&Bs[n][c * 8] =
                *(const uint4*)(Wb + (size_t)n * En + kt * 32 + c * 8);
        }
        __syncthreads();
        bf16x8 af[4], bf[4];
#pragma unroll
        for (int mt = 0; mt < 4; ++mt)
            af[mt] = *(const bf16x8*)&As[mt * 16 + cl][quad * 8];
#pragma unroll
        for (int nt = 0; nt < 4; ++nt)
            bf[nt] = *(const bf16x8*)&Bs[wv * 64 + nt * 16 + cl][quad * 8];
#pragma unroll
        for (int mt = 0; mt < 4; ++mt)
#pragma unroll
            for (int nt = 0; nt < 4; ++nt)
                acc[mt][nt] = __builtin_amdgcn_mfma_f32_16x16x32_bf16(af[mt], bf[nt], acc[mt][nt], 0, 0, 0);
    }
    float bv[4];
#pragma unroll
    for (int nt = 0; nt < 4; ++nt) bv[nt] = bias[wv * 64 + nt * 16 + cl];
#pragma unroll
    for (int mt = 0; mt < 4; ++mt)
#pragma unroll
        for (int nt = 0; nt < 4; ++nt)
#pragma unroll
            for (int r = 0; r < 4; ++r)
                AO[(m0 + mt * 16 + quad * 4 + r) * En + wv * 64 + nt * 16 + cl] =
                    acc[mt][nt][r] + bv[nt];
}

// ---------- K4: boundary MLP -> bscore[b,t] ----------
__global__ __launch_bounds__(256) void k_bscore(const float* __restrict__ ao,
                                                const float* __restrict__ w1,
                                                const float* __restrict__ b1,
                                                const float* __restrict__ w2,
                                                const float* __restrict__ b2,
                                                float* __restrict__ bsc) {
    __shared__ float w1s[32][257];
    __shared__ float as[8][En];
    int tid = threadIdx.x;
    for (int i = tid; i < 32 * En; i += 256) w1s[i >> 8][i & 255] = w1[i];
    int g = tid >> 5, j = tid & 31;
    float b1j = b1[j], w2j = w2[j], b2v = b2[0];
    int tok0 = blockIdx.x * 128;
    for (int r = 0; r < 16; ++r) {
        __syncthreads();
#pragma unroll
        for (int i = 0; i < 2; ++i) {
            int idx = tid + i * 256;               // 0..511
            int row = idx >> 6, pos = (idx & 63) << 2;
            *(float4*)&as[row][pos] =
                *(const float4*)(ao + (size_t)(tok0 + r * 8 + row) * En + pos);
        }
        __syncthreads();
        float ha = 0.f, hb = 0.f;
#pragma unroll
        for (int e = 0; e < En; e += 4) {
            float4 a = *(const float4*)&as[g][e];
            ha += a.x * w1s[j][e];     hb += a.y * w1s[j][e + 1];
            ha += a.z * w1s[j][e + 2]; hb += a.w * w1s[j][e + 3];
        }
        float hv = fmaxf(ha + hb + b1j, 0.f) * w2j;
        hv += __shfl_xor(hv, 16);
        hv += __shfl_xor(hv, 8);
        hv += __shfl_xor(hv, 4);
        hv += __shfl_xor(hv, 2);
        hv += __shfl_xor(hv, 1);
        if (j == 0) bsc[tok0 + r * 8 + g] = 1.f / (1.f + __expf(-(hv + b2v)));
    }
}

// ---------- K5: cumsum -> pid -> segment boundaries (pid monotone!) ----------
__global__ __launch_bounds__(1024) void k_scan(const float* __restrict__ bsc,
                                               int* __restrict__ segs) {
    __shared__ float wsum[16];
    __shared__ float s_pre[1024];
    __shared__ float s_tot;
    int b = blockIdx.x, t = threadIdx.x;
    float x = bsc[b * Tn + t];
#pragma unroll
    for (int d = 1; d < 64; d <<= 1) {
        float y = __shfl_up(x, d);
        if ((t & 63) >= d) x += y;
    }
    int w = t >> 6;
    if ((t & 63) == 63) wsum[w] = x;
    __syncthreads();
    if (t == 0) {
        float s = 0.f;
        for (int i = 0; i < 16; ++i) { float tmp = wsum[i]; wsum[i] = s; s += tmp; }
        s_tot = s;
    }
    __syncthreads();
    float pre = x + wsum[w];
    s_pre[t] = pre;
    __syncthreads();
    float denom = s_tot + 1e-6f;
    float qv = pre / denom * 32.0f;
    int pid = min((int)floorf(qv), 31);
    int pidprev = -1;
    if (t > 0) {
        float qp = s_pre[t - 1] / denom * 32.0f;
        pidprev = min((int)floorf(qp), 31);
    }
    for (int p = pidprev + 1; p <= pid; ++p) segs[b * 33 + p] = t;
    if (t == 1023)
        for (int p = pid + 1; p <= 32; ++p) segs[b * 33 + p] = Tn;
}

// ---------- K6: segment-mean pool + final linear ----------
__global__ __launch_bounds__(256) void k_pool_proj(const float* __restrict__ ao,
                                                   const int* __restrict__ segs,
                                                   const float* __restrict__ prw,
                                                   const float* __restrict__ prb,
                                                   float* __restrict__ out) {
    __shared__ float pes[En];
    int b = blockIdx.y, p = blockIdx.x;
    int s = segs[b * 33 + p];
    int e = segs[b * 33 + p + 1];
    int tid = threadIdx.x;
    float sum = 0.f;
    for (int t = s; t < e; ++t)
        sum += ao[((size_t)b * Tn + t) * En + tid];
    pes[tid] = sum / fmaxf((float)(e - s), 1.f);
    __syncthreads();
    float a0 = prb[tid], a1 = 0.f;
#pragma unroll
    for (int k = 0; k < En; k += 4) {
        float4 wv = *(const float4*)(prw + (size_t)tid * En + k);
        float4 pv = *(const float4*)&pes[k];
        a0 += wv.x * pv.x; a1 += wv.y * pv.y;
        a0 += wv.z * pv.z; a1 += wv.w * pv.w;
    }
    out[((size_t)b * Pn + p) * En + tid] = a0 + a1;
}

extern "C" void kernel_launch(void* const* d_in, const int* in_sizes, int n_in,
                              void* d_out, int out_size, void* d_ws, size_t ws_size,
                              hipStream_t stream) {
    const float* x    = (const float*)d_in[0];
    const float* ipw  = (const float*)d_in[1];
    const float* ipb  = (const float*)d_in[2];
    const float* inw  = (const float*)d_in[3];
    const float* inb  = (const float*)d_in[4];
    const float* outw = (const float*)d_in[5];
    const float* outb = (const float*)d_in[6];
    const float* bw1  = (const float*)d_in[7];
    const float* bb1  = (const float*)d_in[8];
    const float* bw2  = (const float*)d_in[9];
    const float* bb2  = (const float*)d_in[10];
    const float* prw  = (const float*)d_in[11];
    const float* prb  = (const float*)d_in[12];

    // Workspace layout (bytes):
    //  region A [0, 33.5MB): Qb bf16 (16.8MB) + Kb bf16 (16.8MB); later AO fp32
    //  region B [33.5, 50.3MB): Vt bf16
    //  region C [50.3, 83.9MB): Vf fp32; later Ctx fp32
    //  smalls after
    char* base = (char*)d_ws;
    unsigned short* Qb = (unsigned short*)base;                  // 8.4M elts
    unsigned short* Kb = Qb + (size_t)8388608;
    float*          AO = (float*)base;                           // aliases Qb+Kb
    unsigned short* Vt = (unsigned short*)(base + (size_t)33554432);
    float*          Vf = (float*)(base + (size_t)50331648);      // later Ctx
    float*         Ctx = Vf;
    float*          Wc = (float*)(base + (size_t)83886080);      // 24576
    float*          bc = Wc + 24576;                             // 768
    unsigned short* Wb = (unsigned short*)(bc + 768);            // 65536 bf16
    float*         bsc = (float*)(Wb + 65536);                   // 32768
    int*          segs = (int*)(bsc + 32768);                    // 1056

    k_comb_w<<<96, 256, 0, stream>>>(ipw, inw, Wc);
    k_comb_b<<<3, 256, 0, stream>>>(ipb, inw, inb, bc);
    k_wcvt<<<64, 256, 0, stream>>>(outw, Wb);
    k_qkv<<<dim3(3, 256), 256, 0, stream>>>(x, Wc, bc, Qb, Kb, Vf);
    k_vt<<<2048, 256, 0, stream>>>(Vf, Vt);
    k_attn<<<1024, 256, 0, stream>>>(Qb, Kb, Vt, Ctx);           // Ctx over Vf (V dead)
    k_out_mfma<<<512, 256, 0, stream>>>(Ctx, Wb, outb, AO);      // AO over Qb/Kb (dead)
    k_bscore<<<256, 256, 0, stream>>>(AO, bw1, bb1, bw2, bb2, bsc);
    k_scan<<<32, 1024, 0, stream>>>(bsc, segs);
    k_pool_proj<<<dim3(32, 32), 256, 0, stream>>>(AO, segs, prw, prb,
                                                  (float*)d_out);
}

// Round 5
// 244.838 us; speedup vs baseline: 4.3379x; 1.2520x over previous
//
#include <hip/hip_runtime.h>
#include <math.h>

constexpr int Bn  = 32;
constexpr int Tn  = 1024;
constexpr int INn = 32;
constexpr int En  = 256;
constexpr int Pn  = 32;

typedef short bf16x8 __attribute__((ext_vector_type(8)));
typedef float f32x4  __attribute__((ext_vector_type(4)));

__device__ __forceinline__ unsigned short f2bf(float f) {
    unsigned int b = __float_as_uint(f);
    b += 0x7FFF + ((b >> 16) & 1);          // RNE
    return (unsigned short)(b >> 16);
}
__device__ __forceinline__ float bf2f(unsigned short h) {
    return __uint_as_float(((unsigned int)h) << 16);
}

// ---------- K0: fused prep ----------
// blocks [0,96):   Wcb bf16 = (in_proj_w @ ip_w) [768][32]
// blocks [96,99):  bc = in_proj_w @ ip_b + in_proj_b (fp32)
// blocks [99,163): Wb = bf16(out_w) [256][256]
// blocks [163,1187): xb = bf16(x) [32768][32]
// blocks [1187,1219): w1 hi/lo split bf16 [32][256]
__global__ __launch_bounds__(256) void k_prep(const float* __restrict__ ipw,
                                              const float* __restrict__ ipb,
                                              const float* __restrict__ inw,
                                              const float* __restrict__ inb,
                                              const float* __restrict__ outw,
                                              const float* __restrict__ w1,
                                              const float* __restrict__ x,
                                              unsigned short* __restrict__ Wcb,
                                              float* __restrict__ bc,
                                              unsigned short* __restrict__ Wb,
                                              unsigned short* __restrict__ w1h,
                                              unsigned short* __restrict__ w1l,
                                              unsigned short* __restrict__ xb) {
    int blk = blockIdx.x, tid = threadIdx.x;
    if (blk < 96) {
        int idx = blk * 256 + tid;
        int o = idx >> 5, i = idx & 31;
        const float* wr = inw + (size_t)o * En;
        float a0 = 0.f, a1 = 0.f;
        for (int e = 0; e < En; e += 2) {
            a0 += wr[e]     * ipw[(size_t)e * INn + i];
            a1 += wr[e + 1] * ipw[(size_t)(e + 1) * INn + i];
        }
        Wcb[(size_t)o * INn + i] = f2bf(a0 + a1);
    } else if (blk < 99) {
        int o = (blk - 96) * 256 + tid;
        const float* wr = inw + (size_t)o * En;
        float a = inb[o];
        for (int e = 0; e < En; ++e) a += wr[e] * ipb[e];
        bc[o] = a;
    } else if (blk < 163) {
        int idx = (blk - 99) * 256 + tid;          // 16384 float4s
        float4 a = *(const float4*)(outw + (size_t)idx * 4);
        unsigned int u0 = f2bf(a.x) | ((unsigned int)f2bf(a.y) << 16);
        unsigned int u1 = f2bf(a.z) | ((unsigned int)f2bf(a.w) << 16);
        *(uint2*)(Wb + (size_t)idx * 4) = make_uint2(u0, u1);
    } else if (blk < 1187) {
        int idx = (blk - 163) * 256 + tid;         // 262144 float4s
        float4 a = *(const float4*)(x + (size_t)idx * 4);
        unsigned int u0 = f2bf(a.x) | ((unsigned int)f2bf(a.y) << 16);
        unsigned int u1 = f2bf(a.z) | ((unsigned int)f2bf(a.w) << 16);
        *(uint2*)(xb + (size_t)idx * 4) = make_uint2(u0, u1);
    } else {
        int idx = (blk - 1187) * 256 + tid;        // 8192 elements
        float a = w1[idx];
        unsigned short h = f2bf(a);
        w1h[idx] = h;
        w1l[idx] = f2bf(a - bf2f(h));
    }
}

// ---------- K1: qkv projection, pure MFMA, no LDS ----------
// grid 512 (64 tokens each). wave handles 192 out-cols (12 n-tiles), 4 m-tiles.
// Q,K -> bf16 [b,h,t,d]; V -> bf16 transposed [b,h,d,t] (contiguous t stores).
__global__ __launch_bounds__(256, 2) void k_qkv(const unsigned short* __restrict__ xb,
                                                const unsigned short* __restrict__ Wcb,
                                                const float* __restrict__ bc,
                                                unsigned short* __restrict__ Qb,
                                                unsigned short* __restrict__ Kb,
                                                unsigned short* __restrict__ Vt) {
    int tid = threadIdx.x;
    int wv = tid >> 6, lane = tid & 63;
    int cl = lane & 15, quad = lane >> 4;
    int m0 = blockIdx.x * 64;
    int b = m0 >> 10, tl0 = m0 & 1023;
    int n0w = wv * 192;
    f32x4 zero4 = {0.f, 0.f, 0.f, 0.f};

    bf16x8 wfrag[12]; float bv[12];
#pragma unroll
    for (int nt = 0; nt < 12; ++nt) {
        int col = n0w + nt * 16 + cl;
        wfrag[nt] = *(const bf16x8*)(Wcb + (size_t)col * 32 + quad * 8);
        bv[nt] = bc[col];
    }
#pragma unroll
    for (int mt = 0; mt < 4; ++mt) {
        bf16x8 af = *(const bf16x8*)(xb + (size_t)(m0 + mt * 16 + cl) * 32 + quad * 8);
        f32x4 acc[12];
#pragma unroll
        for (int nt = 0; nt < 12; ++nt)
            acc[nt] = __builtin_amdgcn_mfma_f32_16x16x32_bf16(af, wfrag[nt], zero4, 0, 0, 0);
        int tloc = tl0 + mt * 16 + quad * 4;
#pragma unroll
        for (int nt = 0; nt < 12; ++nt) {
            int col = n0w + nt * 16 + cl;
            int slot = col >> 8, c = col & 255;
            int h = c >> 6, d = c & 63;
            int bh = b * 4 + h;
            if (slot == 2) {
                unsigned int u0 = f2bf(acc[nt][0] + bv[nt]) |
                                  ((unsigned int)f2bf(acc[nt][1] + bv[nt]) << 16);
                unsigned int u1 = f2bf(acc[nt][2] + bv[nt]) |
                                  ((unsigned int)f2bf(acc[nt][3] + bv[nt]) << 16);
                *(uint2*)(Vt + ((size_t)bh * 64 + d) * 1024 + tloc) = make_uint2(u0, u1);
            } else {
                unsigned short* dst = (slot ? Kb : Qb) +
                                      ((size_t)bh * 1024 + tloc) * 64 + d;
#pragma unroll
                for (int r = 0; r < 4; ++r)
                    dst[(size_t)r * 64] = f2bf(acc[nt][r] + bv[nt]);
            }
        }
    }
}

// ---------- K2: MFMA flash attention, 64 q-rows per wave ----------
// grid 512: bh = blk & 127 (same-bh blocks share XCD -> L2), qb = blk >> 7.
__global__ __launch_bounds__(256, 2) void k_attn(const unsigned short* __restrict__ Qb,
                                                 const unsigned short* __restrict__ Kb,
                                                 const unsigned short* __restrict__ Vt,
                                                 unsigned short* __restrict__ Ctx) {
    __shared__ unsigned short Ks[64][72];
    __shared__ unsigned short Vs[64][72];
    __shared__ __align__(16) unsigned short Pl[4][4][16][40];
    int blk = blockIdx.x;
    int bh = blk & 127, qb = blk >> 7;
    int b = bh >> 2, h = bh & 3;
    int tid = threadIdx.x;
    int wv = tid >> 6, lane = tid & 63;
    int cl = lane & 15, quad = lane >> 4;
    int qbase = qb * 256 + wv * 64;

    f32x4 zero4 = {0.f, 0.f, 0.f, 0.f};
    bf16x8 qfrag[4][2];
#pragma unroll
    for (int tt = 0; tt < 4; ++tt)
#pragma unroll
        for (int ch = 0; ch < 2; ++ch)
            qfrag[tt][ch] = *(const bf16x8*)(Qb +
                ((size_t)bh * 1024 + qbase + tt * 16 + cl) * 64 + ch * 32 + quad * 8);
    f32x4 acc[4][4];
#pragma unroll
    for (int tt = 0; tt < 4; ++tt)
#pragma unroll
        for (int dt = 0; dt < 4; ++dt) acc[tt][dt] = zero4;
    float l[4] = {0.f, 0.f, 0.f, 0.f};

    const unsigned short* Kbase = Kb + (size_t)bh * 65536;
    const unsigned short* Vbase = Vt + (size_t)bh * 65536;

    for (int kt = 0; kt < 16; ++kt) {
#pragma unroll
        for (int r = 0; r < 2; ++r) {
            int idx = r * 256 + tid; int row = idx >> 3, c16 = idx & 7;
            *(uint4*)&Ks[row][c16 * 8] =
                *(const uint4*)(Kbase + (size_t)(kt * 64 + row) * 64 + c16 * 8);
            *(uint4*)&Vs[row][c16 * 8] =
                *(const uint4*)(Vbase + (size_t)row * 1024 + kt * 64 + c16 * 8);
        }
        __syncthreads();
#pragma unroll
        for (int c = 0; c < 2; ++c) {
            bf16x8 ka0 = *(const bf16x8*)&Ks[c * 32 + cl][quad * 8];
            bf16x8 ka1 = *(const bf16x8*)&Ks[c * 32 + cl][32 + quad * 8];
            bf16x8 kb0 = *(const bf16x8*)&Ks[c * 32 + 16 + cl][quad * 8];
            bf16x8 kb1 = *(const bf16x8*)&Ks[c * 32 + 16 + cl][32 + quad * 8];
            bf16x8 va[4];
#pragma unroll
            for (int dt = 0; dt < 4; ++dt)
                va[dt] = *(const bf16x8*)&Vs[dt * 16 + cl][c * 32 + quad * 8];
#pragma unroll
            for (int tt = 0; tt < 4; ++tt) {
                f32x4 s0 = __builtin_amdgcn_mfma_f32_16x16x32_bf16(ka0, qfrag[tt][0], zero4, 0, 0, 0);
                s0 = __builtin_amdgcn_mfma_f32_16x16x32_bf16(ka1, qfrag[tt][1], s0, 0, 0, 0);
                f32x4 s1 = __builtin_amdgcn_mfma_f32_16x16x32_bf16(kb0, qfrag[tt][0], zero4, 0, 0, 0);
                s1 = __builtin_amdgcn_mfma_f32_16x16x32_bf16(kb1, qfrag[tt][1], s1, 0, 0, 0);
                float p0 = __expf(0.125f * s0[0]), p1 = __expf(0.125f * s0[1]);
                float p2 = __expf(0.125f * s0[2]), p3 = __expf(0.125f * s0[3]);
                float p4 = __expf(0.125f * s1[0]), p5 = __expf(0.125f * s1[1]);
                float p6 = __expf(0.125f * s1[2]), p7 = __expf(0.125f * s1[3]);
                l[tt] += ((p0 + p1) + (p2 + p3)) + ((p4 + p5) + (p6 + p7));
                unsigned int w0 = f2bf(p0) | ((unsigned int)f2bf(p1) << 16);
                unsigned int w1 = f2bf(p2) | ((unsigned int)f2bf(p3) << 16);
                unsigned int w2 = f2bf(p4) | ((unsigned int)f2bf(p5) << 16);
                unsigned int w3 = f2bf(p6) | ((unsigned int)f2bf(p7) << 16);
                *(uint2*)&Pl[wv][tt][cl][quad * 4]      = make_uint2(w0, w1);
                *(uint2*)&Pl[wv][tt][cl][16 + quad * 4] = make_uint2(w2, w3);
            }
            asm volatile("s_waitcnt lgkmcnt(0)" ::: "memory");
#pragma unroll
            for (int tt = 0; tt < 4; ++tt) {
                bf16x8 pf = *(const bf16x8*)&Pl[wv][tt][cl][quad * 8];
#pragma unroll
                for (int dt = 0; dt < 4; ++dt)
                    acc[tt][dt] = __builtin_amdgcn_mfma_f32_16x16x32_bf16(pf, va[dt], acc[tt][dt], 0, 0, 0);
            }
        }
        __syncthreads();
    }
#pragma unroll
    for (int tt = 0; tt < 4; ++tt) {
        l[tt] += __shfl_xor(l[tt], 16);
        l[tt] += __shfl_xor(l[tt], 32);
        l[tt] = 1.f / l[tt];
    }
#pragma unroll
    for (int tt = 0; tt < 4; ++tt) {
#pragma unroll
        for (int r = 0; r < 4; ++r) {
            float rl = __shfl(l[tt], quad * 4 + r);
            size_t row = (size_t)(b * 1024 + qbase + tt * 16 + quad * 4 + r) * En;
#pragma unroll
            for (int dt = 0; dt < 4; ++dt)
                Ctx[row + h * 64 + dt * 16 + cl] = f2bf(acc[tt][dt][r] * rl);
        }
    }
}

// ---------- K3: attn_out = ctx @ out_w^T + out_b  (bf16 MFMA) ----------
__global__ __launch_bounds__(256) void k_out(const unsigned short* __restrict__ Ctx,
                                             const unsigned short* __restrict__ Wb,
                                             const float* __restrict__ bias,
                                             float* __restrict__ AO) {
    __shared__ unsigned short As[64][32];
    __shared__ unsigned short Bs[256][32];
    int tid = threadIdx.x;
    int wv = tid >> 6, lane = tid & 63;
    int cl = lane & 15, quad = lane >> 4;
    size_t m0 = (size_t)blockIdx.x * 64;

    f32x4 acc[4][4];
#pragma unroll
    for (int mt = 0; mt < 4; ++mt)
#pragma unroll
        for (int nt = 0; nt < 4; ++nt) acc[mt][nt] = {0.f, 0.f, 0.f, 0.f};

    for (int kt = 0; kt < 8; ++kt) {
        if (kt) __syncthreads();
        *(uint4*)&As[tid >> 2][(tid & 3) * 8] =
            *(const uint4*)(Ctx + (m0 + (tid >> 2)) * En + kt * 32 + (tid & 3) * 8);
#pragma unroll
        for (int j = 0; j < 4; ++j) {
            int lin = j * 256 + tid; int n = lin >> 2, c = lin & 3;
            *(uint4*)&Bs[n][c * 8] =
                *(const uint4*)(Wb + (size_t)n * En + kt * 32 + c * 8);
        }
        __syncthreads();
        bf16x8 af[4], bfr[4];
#pragma unroll
        for (int mt = 0; mt < 4; ++mt)
            af[mt] = *(const bf16x8*)&As[mt * 16 + cl][quad * 8];
#pragma unroll
        for (int nt = 0; nt < 4; ++nt)
            bfr[nt] = *(const bf16x8*)&Bs[wv * 64 + nt * 16 + cl][quad * 8];
#pragma unroll
        for (int mt = 0; mt < 4; ++mt)
#pragma unroll
            for (int nt = 0; nt < 4; ++nt)
                acc[mt][nt] = __builtin_amdgcn_mfma_f32_16x16x32_bf16(af[mt], bfr[nt], acc[mt][nt], 0, 0, 0);
    }
    float bv[4];
#pragma unroll
    for (int nt = 0; nt < 4; ++nt) bv[nt] = bias[wv * 64 + nt * 16 + cl];
#pragma unroll
    for (int mt = 0; mt < 4; ++mt)
#pragma unroll
        for (int nt = 0; nt < 4; ++nt)
#pragma unroll
            for (int r = 0; r < 4; ++r)
                AO[(m0 + mt * 16 + quad * 4 + r) * En + wv * 64 + nt * 16 + cl] =
                    acc[mt][nt][r] + bv[nt];
}

// ---------- K4: boundary MLP via hi/lo-split bf16 MFMA (~fp32 accurate) ----
// grid 256 (128 tokens each). h1 = AO @ w1^T: 3 MFMAs (hh, hl, lh).
__global__ __launch_bounds__(256) void k_bscore(const float* __restrict__ AO,
                                                const unsigned short* __restrict__ w1h,
                                                const unsigned short* __restrict__ w1l,
                                                const float* __restrict__ b1,
                                                const float* __restrict__ w2,
                                                const float* __restrict__ b2,
                                                float* __restrict__ bsc) {
    __shared__ unsigned short Ah[128][72];
    __shared__ unsigned short Al[128][72];
    int tid = threadIdx.x;
    int wv = tid >> 6, lane = tid & 63;
    int cl = lane & 15, quad = lane >> 4;
    int m0 = blockIdx.x * 128;

    f32x4 acc[2][2];
#pragma unroll
    for (int mt = 0; mt < 2; ++mt)
#pragma unroll
        for (int nt = 0; nt < 2; ++nt) acc[mt][nt] = {0.f, 0.f, 0.f, 0.f};

    for (int kt = 0; kt < 4; ++kt) {               // BK = 64
        if (kt) __syncthreads();
#pragma unroll
        for (int j = 0; j < 8; ++j) {
            int lin = j * 256 + tid; int row = lin >> 4, c4 = lin & 15;
            float4 a = *(const float4*)(AO + (size_t)(m0 + row) * En + kt * 64 + c4 * 4);
            unsigned short h0 = f2bf(a.x), h1v = f2bf(a.y), h2 = f2bf(a.z), h3 = f2bf(a.w);
            unsigned short l0 = f2bf(a.x - bf2f(h0)), l1v = f2bf(a.y - bf2f(h1v));
            unsigned short l2 = f2bf(a.z - bf2f(h2)), l3 = f2bf(a.w - bf2f(h3));
            *(uint2*)&Ah[row][c4 * 4] =
                make_uint2(h0 | ((unsigned int)h1v << 16), h2 | ((unsigned int)h3 << 16));
            *(uint2*)&Al[row][c4 * 4] =
                make_uint2(l0 | ((unsigned int)l1v << 16), l2 | ((unsigned int)l3 << 16));
        }
        __syncthreads();
#pragma unroll
        for (int ks = 0; ks < 2; ++ks) {
            bf16x8 bh_[2], bl_[2];
#pragma unroll
            for (int nt = 0; nt < 2; ++nt) {
                size_t off = (size_t)(nt * 16 + cl) * En + kt * 64 + ks * 32 + quad * 8;
                bh_[nt] = *(const bf16x8*)(w1h + off);
                bl_[nt] = *(const bf16x8*)(w1l + off);
            }
#pragma unroll
            for (int mt = 0; mt < 2; ++mt) {
                int row = wv * 32 + mt * 16 + cl;
                bf16x8 ah = *(const bf16x8*)&Ah[row][ks * 32 + quad * 8];
                bf16x8 al = *(const bf16x8*)&Al[row][ks * 32 + quad * 8];
#pragma unroll
                for (int nt = 0; nt < 2; ++nt) {
                    acc[mt][nt] = __builtin_amdgcn_mfma_f32_16x16x32_bf16(ah, bh_[nt], acc[mt][nt], 0, 0, 0);
                    acc[mt][nt] = __builtin_amdgcn_mfma_f32_16x16x32_bf16(ah, bl_[nt], acc[mt][nt], 0, 0, 0);
                    acc[mt][nt] = __builtin_amdgcn_mfma_f32_16x16x32_bf16(al, bh_[nt], acc[mt][nt], 0, 0, 0);
                }
            }
        }
    }
    float b1v[2], w2v[2];
#pragma unroll
    for (int nt = 0; nt < 2; ++nt) {
        b1v[nt] = b1[nt * 16 + cl];
        w2v[nt] = w2[nt * 16 + cl];
    }
    float b2v = b2[0];
#pragma unroll
    for (int mt = 0; mt < 2; ++mt) {
        f32x4 z;
#pragma unroll
        for (int r = 0; r < 4; ++r)
            z[r] = fmaxf(acc[mt][0][r] + b1v[0], 0.f) * w2v[0] +
                   fmaxf(acc[mt][1][r] + b1v[1], 0.f) * w2v[1];
#pragma unroll
        for (int d = 1; d < 16; d <<= 1)
#pragma unroll
            for (int r = 0; r < 4; ++r) z[r] += __shfl_xor(z[r], d);
        if (cl == 0) {
#pragma unroll
            for (int r = 0; r < 4; ++r)
                bsc[m0 + wv * 32 + mt * 16 + quad * 4 + r] =
                    1.f / (1.f + __expf(-(z[r] + b2v)));
        }
    }
}

// ---------- K5: cumsum -> pid -> segment boundaries (pid monotone!) ----------
__global__ __launch_bounds__(1024) void k_scan(const float* __restrict__ bsc,
                                               int* __restrict__ segs) {
    __shared__ float wsum[16];
    __shared__ float s_pre[1024];
    __shared__ float s_tot;
    int b = blockIdx.x, t = threadIdx.x;
    float x = bsc[b * Tn + t];
#pragma unroll
    for (int d = 1; d < 64; d <<= 1) {
        float y = __shfl_up(x, d);
        if ((t & 63) >= d) x += y;
    }
    int w = t >> 6;
    if ((t & 63) == 63) wsum[w] = x;
    __syncthreads();
    if (t == 0) {
        float s = 0.f;
        for (int i = 0; i < 16; ++i) { float tmp = wsum[i]; wsum[i] = s; s += tmp; }
        s_tot = s;
    }
    __syncthreads();
    float pre = x + wsum[w];
    s_pre[t] = pre;
    __syncthreads();
    float denom = s_tot + 1e-6f;
    float qv = pre / denom * 32.0f;
    int pid = min((int)floorf(qv), 31);
    int pidprev = -1;
    if (t > 0) {
        float qp = s_pre[t - 1] / denom * 32.0f;
        pidprev = min((int)floorf(qp), 31);
    }
    for (int p = pidprev + 1; p <= pid; ++p) segs[b * 33 + p] = t;
    if (t == 1023)
        for (int p = pid + 1; p <= 32; ++p) segs[b * 33 + p] = Tn;
}

// ---------- K6: segment-mean pool + final linear ----------
__global__ __launch_bounds__(256) void k_pool_proj(const float* __restrict__ ao,
                                                   const int* __restrict__ segs,
                                                   const float* __restrict__ prw,
                                                   const float* __restrict__ prb,
                                                   float* __restrict__ out) {
    __shared__ float pes[En];
    int b = blockIdx.y, p = blockIdx.x;
    int s = segs[b * 33 + p];
    int e = segs[b * 33 + p + 1];
    int tid = threadIdx.x;
    float sum = 0.f;
    for (int t = s; t < e; ++t)
        sum += ao[((size_t)b * Tn + t) * En + tid];
    pes[tid] = sum / fmaxf((float)(e - s), 1.f);
    __syncthreads();
    float a0 = prb[tid], a1 = 0.f;
#pragma unroll
    for (int k = 0; k < En; k += 4) {
        float4 wv = *(const float4*)(prw + (size_t)tid * En + k);
        float4 pv = *(const float4*)&pes[k];
        a0 += wv.x * pv.x; a1 += wv.y * pv.y;
        a0 += wv.z * pv.z; a1 += wv.w * pv.w;
    }
    out[((size_t)b * Pn + p) * En + tid] = a0 + a1;
}

extern "C" void kernel_launch(void* const* d_in, const int* in_sizes, int n_in,
                              void* d_out, int out_size, void* d_ws, size_t ws_size,
                              hipStream_t stream) {
    const float* x    = (const float*)d_in[0];
    const float* ipw  = (const float*)d_in[1];
    const float* ipb  = (const float*)d_in[2];
    const float* inw  = (const float*)d_in[3];
    const float* inb  = (const float*)d_in[4];
    const float* outw = (const float*)d_in[5];
    const float* outb = (const float*)d_in[6];
    const float* bw1  = (const float*)d_in[7];
    const float* bb1  = (const float*)d_in[8];
    const float* bw2  = (const float*)d_in[9];
    const float* bb2  = (const float*)d_in[10];
    const float* prw  = (const float*)d_in[11];
    const float* prb  = (const float*)d_in[12];

    // Workspace layout (bytes):
    //  [0, 16.8M): Qb bf16          } AO fp32 (33.5M) overlays Qb+Kb after attn
    //  [16.8M, 33.6M): Kb bf16      }
    //  [33.6M, 50.3M): Vt bf16 [b,h,d,t]
    //  [50.3M, 67.1M): Ctx bf16 [t,256]
    //  [67.1M, ...): xb, Wcb, bc, Wb, w1h, w1l, bsc, segs
    char* base = (char*)d_ws;
    unsigned short* Qb  = (unsigned short*)base;
    unsigned short* Kb  = Qb + (size_t)8388608;
    float*          AO  = (float*)base;
    unsigned short* Vt  = (unsigned short*)(base + (size_t)33554432);
    unsigned short* Ctx = (unsigned short*)(base + (size_t)50331648);
    unsigned short* xb  = (unsigned short*)(base + (size_t)67108864);   // 2 MB
    unsigned short* Wcb = (unsigned short*)(base + (size_t)69206016);   // 48 KB
    float*          bc  = (float*)(base + (size_t)69255168);            // 3 KB
    unsigned short* Wb  = (unsigned short*)(base + (size_t)69258240);   // 128 KB
    unsigned short* w1h = (unsigned short*)(base + (size_t)69389312);   // 16 KB
    unsigned short* w1l = (unsigned short*)(base + (size_t)69405696);   // 16 KB
    float*          bsc = (float*)(base + (size_t)69422080);            // 128 KB
    int*           segs = (int*)(base + (size_t)69553152);              // 4.2 KB

    k_prep<<<1219, 256, 0, stream>>>(ipw, ipb, inw, inb, outw, bw1, x,
                                     Wcb, bc, Wb, w1h, w1l, xb);
    k_qkv<<<512, 256, 0, stream>>>(xb, Wcb, bc, Qb, Kb, Vt);
    k_attn<<<512, 256, 0, stream>>>(Qb, Kb, Vt, Ctx);
    k_out<<<512, 256, 0, stream>>>(Ctx, Wb, outb, AO);      // AO over Qb/Kb (dead)
    k_bscore<<<256, 256, 0, stream>>>(AO, w1h, w1l, bb1, bw2, bb2, bsc);
    k_scan<<<32, 1024, 0, stream>>>(bsc, segs);
    k_pool_proj<<<dim3(32, 32), 256, 0, stream>>>(AO, segs, prw, prb,
                                                  (float*)d_out);
}